// Round 8
// baseline (132.508 us; speedup 1.0000x reference)
//
#include <hip/hip_runtime.h>
#include <hip/hip_bf16.h>

#define MQ 32
#define NG 256
#define DD 128

// full-wave butterfly reduction (64 lanes)
__device__ __forceinline__ float wred64(float v) {
    #pragma unroll
    for (int o = 32; o > 0; o >>= 1) v += __shfl_xor(v, o);
    return v;
}

template<bool ZE0>
__device__ __forceinline__ void core16(const float* __restrict__ mp_g,
                                       const float* __restrict__ ua_g,
                                       const float ze,
                                       const float ub[4][4],
                                       float acc[4], float& msum) {
    // Fully unrolled: ds_read/global_load offsets become immediates,
    // no per-step pointer arithmetic in the issue stream.
    #pragma unroll
    for (int s = 0; s < 16; ++s) {
        const float4 mp = *(const float4*)(mp_g + (size_t)s * 2 * DD); // L2 hit
        const float4 ua = *(const float4*)(ua_g + s * 8);              // LDS b128
        msum += (mp.x + mp.y) + (mp.z + mp.w);
        float m0, m1, m2, m3;
        if (ZE0) { m0 = mp.x; m1 = mp.y; m2 = mp.z; m3 = mp.w; }
        else     { m0 = mp.x + ze; m1 = mp.y + ze; m2 = mp.z + ze; m3 = mp.w + ze; }
        const float ua4[4] = {ua.x, ua.y, ua.z, ua.w};
        #pragma unroll
        for (int p = 0; p < 4; ++p) {
            acc[p] += __builtin_fabsf(fmaf(ua4[p], ub[p][0], -m0));
            acc[p] += __builtin_fabsf(fmaf(ua4[p], ub[p][1], -m1));
            acc[p] += __builtin_fabsf(fmaf(ua4[p], ub[p][2], -m2));
            acc[p] += __builtin_fabsf(fmaf(ua4[p], ub[p][3], -m3));
        }
    }
}

__global__ __launch_bounds__(256, 8)   // pin VGPR <= 64: keep 8 waves/SIMD
void InferenceXtt_kernel(const float* __restrict__ qf,
                         const float* __restrict__ x,
                         const float* __restrict__ Mp,
                         const float* __restrict__ zep,
                         float* __restrict__ out) {
    __shared__ float u_T[DD][4];            // 2 KB: u_T[d][p]
    __shared__ float su_sh[4], dist0_sh[4];
    __shared__ float pen_sh[4][4];
    __shared__ float msum_sh[4];

    const int t = threadIdx.x;
    const int w = t >> 6;                  // wave 0..3
    const int l = t & 63;
    const int k = l & 31;
    const int d0 = k * 4;                  // this lane's 4 b-columns
    const int half = l >> 5;
    const int i  = blockIdx.x >> 6;        // query 0..31
    const int j0 = (blockIdx.x & 63) * 4;  // 4 pairs per block

    const float ze = zep[0];

    // ---- prep: wave w owns pair p=w; coalesced scalar loads; u into LDS ----
    {
        const float q0 = qf[i * DD + l];
        const float q1 = qf[i * DD + l + 64];
        const float x0 = x[(j0 + w) * DD + l];
        const float x1 = x[(j0 + w) * DD + l + 64];
        const float u0 = fmaxf(q0, x0), u1 = fmaxf(q1, x1);
        const float v0 = fminf(q0, x0), v1 = fminf(q1, x1);
        u_T[l][w]      = u0;
        u_T[l + 64][w] = u1;
        const float su = wred64(u0 + u1);
        const float sv = wred64(v0 + v1);
        if (l == 0) { su_sh[w] = su; dist0_sh[w] = sv / su; }
    }
    __syncthreads();   // u_T ready

    // ---- ub register tile straight from u_T ----
    float ub[4][4];    // ub[p][c] = u[d0+c] for pair p
    #pragma unroll
    for (int c = 0; c < 4; ++c) {
        const float4 uu = *(const float4*)&u_T[d0 + c][0];
        ub[0][c] = uu.x; ub[1][c] = uu.y; ub[2][c] = uu.z; ub[3][c] = uu.w;
    }

    // ---- core: wave w owns rows w*32..w*32+31; 2 rows/step, 16 steps ----
    float acc[4] = {0.f, 0.f, 0.f, 0.f};
    float msum = 0.f;
    const float* mp_g = &Mp[(w * 32 + half) * DD + d0];
    const float* ua_g = &u_T[w * 32 + half][0];
    if (ze == 0.f) core16<true >(mp_g, ua_g, ze, ub, acc, msum);  // wave-uniform
    else           core16<false>(mp_g, ua_g, ze, ub, acc, msum);

    // ---- reductions ----
    #pragma unroll
    for (int p = 0; p < 4; ++p) {
        const float S = wred64(acc[p]);
        if (l == p) pen_sh[w][p] = S;
    }
    const float ms = wred64(msum);
    if (l == 0) msum_sh[w] = ms;
    __syncthreads();

    if (t < 4) {
        float S = 0.f, sumMp = 0.f;
        #pragma unroll
        for (int ww = 0; ww < 4; ++ww) { S += pen_sh[ww][t]; sumMp += msum_sh[ww]; }
        const float su = su_sh[t];
        // pen = 16384*ze + 0.5*(su^2 - sum(Mp+ze) + S) = 8192*ze + 0.5*(su^2 - sumMp + S)
        const float pen = 8192.f * ze + 0.5f * (fmaf(su, su, -sumMp) + S);
        out[i * NG + j0 + t] = dist0_sh[t] - 0.001f * pen;
    }
}

extern "C" void kernel_launch(void* const* d_in, const int* in_sizes, int n_in,
                              void* d_out, int out_size, void* d_ws, size_t ws_size,
                              hipStream_t stream) {
    const float* qf = (const float*)d_in[0];
    const float* x  = (const float*)d_in[1];
    const float* Mp = (const float*)d_in[2];
    const float* ze = (const float*)d_in[3];
    float* out = (float*)d_out;
    InferenceXtt_kernel<<<dim3(MQ * 64), dim3(256), 0, stream>>>(qf, x, Mp, ze, out);
}

// Round 9
// 19.082 us; speedup vs baseline: 6.9443x; 6.9443x over previous
//
#include <hip/hip_runtime.h>
#include <hip/hip_fp16.h>

#define MQ 32
#define NG 256
#define DD 128

// full-wave butterfly reduction (64 lanes)
__device__ __forceinline__ float wred64(float v) {
    #pragma unroll
    for (int o = 32; o > 0; o >>= 1) v += __shfl_xor(v, o);
    return v;
}
// half-wave reduction (32 lanes)
__device__ __forceinline__ float hred32(float v) {
    #pragma unroll
    for (int o = 16; o > 0; o >>= 1) v += __shfl_xor(v, o);
    return v;
}

__global__ __launch_bounds__(256)
void InferenceXtt_kernel(const float* __restrict__ qf,
                         const float* __restrict__ x,
                         const float* __restrict__ Mp,
                         const float* __restrict__ zep,
                         float* __restrict__ out) {
    __shared__ __half  negm_sh[DD * DD];     // 32 KB: -(Mp+ze) in f16, row-major
    __shared__ __half2 ua_sh[DD][8];         // 4 KB: splat (u,u) per (row d, pair p)
    __shared__ __half2 ucp_sh[DD / 2][8];    // 2 KB: (u[2c],u[2c+1]) per pair
    __shared__ float suh_sh[8], dist0_sh[8], pen_sh[4][8], msum_sh[4];

    const int t = threadIdx.x;
    const int w = t >> 6, l = t & 63, k = l & 31, half = l >> 5;
    const int d0 = k * 4;
    const int i  = blockIdx.x >> 5;        // query 0..31
    const int j0 = (blockIdx.x & 31) * 8;  // 8 pairs per block

    const float ze = zep[0];

    // ---- prep A: u for 8 pairs; half-wave group p = t>>5 owns pair p ----
    {
        const int p = t >> 5;
        const float4 qv = *(const float4*)&qf[i * DD + d0];
        const float4 xv = *(const float4*)&x[(j0 + p) * DD + d0];
        const float u0 = fmaxf(qv.x, xv.x), u1 = fmaxf(qv.y, xv.y);
        const float u2 = fmaxf(qv.z, xv.z), u3 = fmaxf(qv.w, xv.w);
        const float v0 = fminf(qv.x, xv.x), v1 = fminf(qv.y, xv.y);
        const float v2 = fminf(qv.z, xv.z), v3 = fminf(qv.w, xv.w);
        const __half h0 = __float2half(u0), h1 = __float2half(u1);
        const __half h2 = __float2half(u2), h3 = __float2half(u3);
        ua_sh[d0 + 0][p] = __half2half2(h0);
        ua_sh[d0 + 1][p] = __half2half2(h1);
        ua_sh[d0 + 2][p] = __half2half2(h2);
        ua_sh[d0 + 3][p] = __half2half2(h3);
        ucp_sh[k * 2 + 0][p] = __halves2half2(h0, h1);
        ucp_sh[k * 2 + 1][p] = __halves2half2(h2, h3);
        // su_h: sum of the f16-ROUNDED u (for the pen identity, self-consistent)
        const float suh = hred32((__half2float(h0) + __half2float(h1)) +
                                 (__half2float(h2) + __half2float(h3)));
        const float su  = hred32((u0 + u1) + (u2 + u3));   // f32, for dist0
        const float sv  = hred32((v0 + v1) + (v2 + v3));
        if (k == 0) { suh_sh[p] = suh; dist0_sh[p] = sv / su; }
    }

    // ---- prep B: stage -(Mp+ze) as f16; msneg = sum of the STORED values ----
    {
        float ms = 0.f;
        const float4* g = (const float4*)Mp;
        #pragma unroll 4
        for (int r = 0; r < 16; ++r) {
            const int f = t + r * 256;          // float4 index, coalesced
            const float4 v = g[f];
            union { __half2 h[2]; uint2 u; } pk;
            pk.h[0] = __floats2half2_rn(-(v.x + ze), -(v.y + ze));
            pk.h[1] = __floats2half2_rn(-(v.z + ze), -(v.w + ze));
            *(uint2*)&negm_sh[4 * f] = pk.u;
            // accumulate exactly what the core will consume (converted back)
            ms += (__low2float(pk.h[0]) + __high2float(pk.h[0]))
                + (__low2float(pk.h[1]) + __high2float(pk.h[1]));
        }
        ms = wred64(ms);
        if (l == 0) msum_sh[w] = ms;
    }
    __syncthreads();

    // ---- ub2 register tile: column-pairs for this lane's 4 cols x 8 pairs ----
    __half2 ub2[8][2];
    #pragma unroll
    for (int cg = 0; cg < 2; ++cg) {
        union { uint4 u; __half2 h[4]; } A, B;
        A.u = *(const uint4*)&ucp_sh[k * 2 + cg][0];
        B.u = *(const uint4*)&ucp_sh[k * 2 + cg][4];
        #pragma unroll
        for (int p = 0; p < 4; ++p) { ub2[p][cg] = A.h[p]; ub2[p + 4][cg] = B.h[p]; }
    }

    // ---- packed core: wave w rows w*32..+31; 1 row x 4 cols x 8 pairs per step ----
    __half2 acc2[8][2];
    #pragma unroll
    for (int p = 0; p < 8; ++p)
        acc2[p][0] = acc2[p][1] = __floats2half2_rn(0.f, 0.f);

    const __half*  mrow  = &negm_sh[(w * 32 + half) * DD + d0];
    const __half2* uarow = &ua_sh[w * 32 + half][0];
    #pragma unroll 4
    for (int s = 0; s < 16; ++s) {
        union { uint2 u; __half2 h[2]; } M;
        M.u = *(const uint2*)mrow;                 // ds_read_b64, 2-way free
        union { uint4 u; __half2 h[4]; } A, B;
        A.u = *(const uint4*)uarow;                // broadcast b128
        B.u = *(const uint4*)(uarow + 4);
        mrow  += 2 * DD;
        uarow += 2 * 8;
        #pragma unroll
        for (int p = 0; p < 8; ++p) {
            const __half2 ua2 = (p < 4) ? A.h[p] : B.h[p - 4];
            const __half2 w01 = __hfma2(ua2, ub2[p][0], M.h[0]);  // m pre-negated
            const __half2 w23 = __hfma2(ua2, ub2[p][1], M.h[1]);
            acc2[p][0] = __hadd2(acc2[p][0], __habs2(w01));
            acc2[p][1] = __hadd2(acc2[p][1], __habs2(w23));
        }
    }

    // ---- reductions ----
    #pragma unroll
    for (int p = 0; p < 8; ++p) {
        const float S = (__low2float(acc2[p][0]) + __high2float(acc2[p][0]))
                      + (__low2float(acc2[p][1]) + __high2float(acc2[p][1]));
        const float Sr = wred64(S);
        if (l == p) pen_sh[w][p] = Sr;
    }
    __syncthreads();

    if (t < 8) {
        float S = 0.f, msneg = 0.f;
        #pragma unroll
        for (int ww = 0; ww < 4; ++ww) { S += pen_sh[ww][t]; msneg += msum_sh[ww]; }
        const float suh = suh_sh[t];
        // pen = 16384*ze + 0.5*(Sum_w + Sum|w|), Sum_w = suh^2 + msneg (all f16-consistent)
        const float pen = 16384.f * ze + 0.5f * (fmaf(suh, suh, msneg) + S);
        out[i * NG + j0 + t] = dist0_sh[t] - 0.001f * pen;
    }
}

extern "C" void kernel_launch(void* const* d_in, const int* in_sizes, int n_in,
                              void* d_out, int out_size, void* d_ws, size_t ws_size,
                              hipStream_t stream) {
    const float* qf = (const float*)d_in[0];
    const float* x  = (const float*)d_in[1];
    const float* Mp = (const float*)d_in[2];
    const float* ze = (const float*)d_in[3];
    float* out = (float*)d_out;
    InferenceXtt_kernel<<<dim3(MQ * 32), dim3(256), 0, stream>>>(qf, x, Mp, ze, out);
}

// Round 11
// 17.606 us; speedup vs baseline: 7.5261x; 1.0838x over previous
//
#include <hip/hip_runtime.h>
#include <hip/hip_fp16.h>

#define MQ 32
#define NG 256
#define DD 128

typedef __fp16 fp16x2 __attribute__((ext_vector_type(2)));
union H2U { fp16x2 v; __half2 h; unsigned int u; };

__device__ __forceinline__ __half2 cvt_pkrtz(float a, float b) {
    H2U r; r.v = __builtin_amdgcn_cvt_pkrtz(a, b); return r.h;
}

// full-wave butterfly reduction (64 lanes)
__device__ __forceinline__ float wred64(float v) {
    #pragma unroll
    for (int o = 32; o > 0; o >>= 1) v += __shfl_xor(v, o);
    return v;
}

template<bool ZE0>
__device__ __forceinline__ void core16(const float* __restrict__ mp_g,
                                       const __half2* __restrict__ ua_g,
                                       const float ze,
                                       const __half2 ub2[4][2],
                                       __half2 acc2[4][2], float& msum) {
    #pragma unroll 4
    for (int s = 0; s < 16; ++s) {
        const float4 mp = *(const float4*)mp_g;        // global dwordx4, L2 hit
        union { uint4 u; __half2 h[4]; } A;
        A.u = *(const uint4*)ua_g;                     // ds_read_b128, 2-addr broadcast
        mp_g += 2 * DD;
        ua_g += 2 * 4;
        msum += (mp.x + mp.y) + (mp.z + mp.w);
        __half2 nm01, nm23;                            // -(Mp+ze) packed; neg folds into cvt
        if (ZE0) { nm01 = cvt_pkrtz(-mp.x, -mp.y);
                   nm23 = cvt_pkrtz(-mp.z, -mp.w); }
        else     { nm01 = cvt_pkrtz(-(mp.x + ze), -(mp.y + ze));
                   nm23 = cvt_pkrtz(-(mp.z + ze), -(mp.w + ze)); }
        #pragma unroll
        for (int p = 0; p < 4; ++p) {
            const __half2 w01 = __hfma2(A.h[p], ub2[p][0], nm01);
            const __half2 w23 = __hfma2(A.h[p], ub2[p][1], nm23);
            acc2[p][0] = __hadd2(acc2[p][0], __habs2(w01));
            acc2[p][1] = __hadd2(acc2[p][1], __habs2(w23));
        }
    }
}

__global__ __launch_bounds__(256)
void InferenceXtt_kernel(const float* __restrict__ qf,
                         const float* __restrict__ x,
                         const float* __restrict__ Mp,
                         const float* __restrict__ zep,
                         float* __restrict__ out) {
    __shared__ __half2 ua_sh[DD][4];        // 2 KB: splat (u,u) per (row d, pair p)
    __shared__ float suh_sh[4], dist0_sh[4];
    __shared__ float pen_sh[4][4], msum_sh[4];

    const int t = threadIdx.x;
    const int w = t >> 6;                  // wave 0..3
    const int l = t & 63;
    const int k = l & 31;
    const int d0 = k * 4;                  // this lane's 4 b-columns
    const int half = l >> 5;
    const int i  = blockIdx.x >> 6;        // query 0..31
    const int j0 = (blockIdx.x & 63) * 4;  // 4 pairs per block

    const float ze = zep[0];

    // ---- prep: wave w owns pair p=w; coalesced scalar loads; RTZ splats to LDS ----
    {
        const float q0 = qf[i * DD + l];
        const float q1 = qf[i * DD + l + 64];
        const float x0 = x[(j0 + w) * DD + l];
        const float x1 = x[(j0 + w) * DD + l + 64];
        const float u0 = fmaxf(q0, x0), u1 = fmaxf(q1, x1);
        const float v0 = fminf(q0, x0), v1 = fminf(q1, x1);
        const __half2 s0 = cvt_pkrtz(u0, u0);     // splat, RTZ
        const __half2 s1 = cvt_pkrtz(u1, u1);
        ua_sh[l][w]      = s0;
        ua_sh[l + 64][w] = s1;
        const float uh0 = __half2float(__low2half(s0));   // rounded-back values
        const float uh1 = __half2float(__low2half(s1));
        const float su  = wred64(u0 + u1);        // f32 for dist0
        const float sv  = wred64(v0 + v1);
        const float suh = wred64(uh0 + uh1);      // sum of RTZ-rounded u (identity)
        if (l == 0) { dist0_sh[w] = sv / su; suh_sh[w] = suh; }
    }

    // ---- ub2 register tile from global (same RTZ rounding as ua_sh) ----
    __half2 ub2[4][2];
    {
        const float4 qv = *(const float4*)&qf[i * DD + d0];
        #pragma unroll
        for (int p = 0; p < 4; ++p) {
            const float4 xv = *(const float4*)&x[(j0 + p) * DD + d0];
            ub2[p][0] = cvt_pkrtz(fmaxf(qv.x, xv.x), fmaxf(qv.y, xv.y));
            ub2[p][1] = cvt_pkrtz(fmaxf(qv.z, xv.z), fmaxf(qv.w, xv.w));
        }
    }

    __syncthreads();   // ua_sh ready

    // ---- packed core: wave w rows w*32..+31; 2 rows/step (half), 16 steps ----
    __half2 acc2[4][2];
    #pragma unroll
    for (int p = 0; p < 4; ++p) acc2[p][0] = acc2[p][1] = __half2half2(__float2half(0.f));
    float msum = 0.f;

    const float*   mp_g = &Mp[(w * 32 + half) * DD + d0];
    const __half2* ua_g = &ua_sh[w * 32 + half][0];
    if (ze == 0.f) core16<true >(mp_g, ua_g, ze, ub2, acc2, msum);  // wave-uniform
    else           core16<false>(mp_g, ua_g, ze, ub2, acc2, msum);

    // ---- reductions ----
    #pragma unroll
    for (int p = 0; p < 4; ++p) {
        const float S = (__low2float(acc2[p][0]) + __high2float(acc2[p][0]))
                      + (__low2float(acc2[p][1]) + __high2float(acc2[p][1]));
        const float Sr = wred64(S);
        if (l == p) pen_sh[w][p] = Sr;
    }
    const float ms = wred64(msum);
    if (l == 0) msum_sh[w] = ms;
    __syncthreads();

    if (t < 4) {
        float S = 0.f, sumMp = 0.f;
        #pragma unroll
        for (int ww = 0; ww < 4; ++ww) { S += pen_sh[ww][t]; sumMp += msum_sh[ww]; }
        const float suh = suh_sh[t];
        // pen = 16384*ze + 0.5*(suh^2 - sum(Mp+ze) + S) = 8192*ze + 0.5*(suh^2 - sumMp + S)
        const float pen = 8192.f * ze + 0.5f * (fmaf(suh, suh, -sumMp) + S);
        out[i * NG + j0 + t] = dist0_sh[t] - 0.001f * pen;
    }
}

extern "C" void kernel_launch(void* const* d_in, const int* in_sizes, int n_in,
                              void* d_out, int out_size, void* d_ws, size_t ws_size,
                              hipStream_t stream) {
    const float* qf = (const float*)d_in[0];
    const float* x  = (const float*)d_in[1];
    const float* Mp = (const float*)d_in[2];
    const float* ze = (const float*)d_in[3];
    float* out = (float*)d_out;
    InferenceXtt_kernel<<<dim3(MQ * 64), dim3(256), 0, stream>>>(qf, x, Mp, ze, out);
}

// Round 13
// 15.807 us; speedup vs baseline: 8.3830x; 1.1139x over previous
//
#include <hip/hip_runtime.h>
#include <hip/hip_fp16.h>

#define MQ 32
#define NG 256
#define DD 128

typedef __fp16 fp16x2 __attribute__((ext_vector_type(2)));
union H2U { fp16x2 v; __half2 h; unsigned int u; };

__device__ __forceinline__ __half2 cvt_pkrtz(float a, float b) {
    H2U r; r.v = __builtin_amdgcn_cvt_pkrtz(a, b); return r.h;
}

// packed f16 max -> v_pk_max_f16 (ROCm headers lack __hmax2)
__device__ __forceinline__ __half2 hmax2(__half2 a, __half2 b) {
    H2U x, y, r; x.h = a; y.h = b;
    r.v = __builtin_elementwise_max(x.v, y.v);
    return r.h;
}

// full-wave butterfly reduction (64 lanes)
__device__ __forceinline__ float wred64(float v) {
    #pragma unroll
    for (int o = 32; o > 0; o >>= 1) v += __shfl_xor(v, o);
    return v;
}

__global__ __launch_bounds__(256)
void InferenceXtt_kernel(const float* __restrict__ qf,
                         const float* __restrict__ x,
                         const float* __restrict__ Mp,
                         const float* __restrict__ zep,
                         float* __restrict__ out) {
    __shared__ __half2 ua_sh[DD][4];        // 2 KB: splat (u,u) per (row d, pair p)
    __shared__ float dist0_sh[4];
    __shared__ float pen_sh[4][4];

    const int t = threadIdx.x;
    const int w = t >> 6;                  // wave 0..3
    const int l = t & 63;
    const int k = l & 31;
    const int d0 = k * 4;                  // this lane's 4 b-columns
    const int half = l >> 5;
    const int i  = blockIdx.x >> 6;        // query 0..31
    const int j0 = (blockIdx.x & 63) * 4;  // 4 pairs per block

    const float ze = zep[0];
    const __half2 ze2 = cvt_pkrtz(ze, ze); // f16 clamp threshold (splat)

    // ---- prep: wave w owns pair p=w; coalesced scalar loads; RTZ splats to LDS ----
    {
        const float q0 = qf[i * DD + l];
        const float q1 = qf[i * DD + l + 64];
        const float x0 = x[(j0 + w) * DD + l];
        const float x1 = x[(j0 + w) * DD + l + 64];
        const float u0 = fmaxf(q0, x0), u1 = fmaxf(q1, x1);
        const float v0 = fminf(q0, x0), v1 = fminf(q1, x1);
        ua_sh[l][w]      = cvt_pkrtz(u0, u0);   // splat, RTZ
        ua_sh[l + 64][w] = cvt_pkrtz(u1, u1);
        const float su = wred64(u0 + u1);       // f32 for dist0
        const float sv = wred64(v0 + v1);
        if (l == 0) dist0_sh[w] = sv / su;
    }

    // ---- ub2 register tile from global (same RTZ rounding as ua_sh) ----
    __half2 ub2[4][2];
    {
        const float4 qv = *(const float4*)&qf[i * DD + d0];
        #pragma unroll
        for (int p = 0; p < 4; ++p) {
            const float4 xv = *(const float4*)&x[(j0 + p) * DD + d0];
            ub2[p][0] = cvt_pkrtz(fmaxf(qv.x, xv.x), fmaxf(qv.y, xv.y));
            ub2[p][1] = cvt_pkrtz(fmaxf(qv.z, xv.z), fmaxf(qv.w, xv.w));
        }
    }

    __syncthreads();   // ua_sh ready

    // ---- packed core: acc += max(ze, fma(ua, ub, -m)) directly ----
    __half2 acc2[4][2];
    #pragma unroll
    for (int p = 0; p < 4; ++p) acc2[p][0] = acc2[p][1] = __half2half2(__float2half(0.f));

    const float*   mp_g = &Mp[(w * 32 + half) * DD + d0];
    const __half2* ua_g = &ua_sh[w * 32 + half][0];
    #pragma unroll 4
    for (int s = 0; s < 16; ++s) {
        const float4 mp = *(const float4*)mp_g;        // global dwordx4, L2 hit
        union { uint4 u; __half2 h[4]; } A;
        A.u = *(const uint4*)ua_g;                     // ds_read_b128 broadcast
        mp_g += 2 * DD;
        ua_g += 2 * 4;
        const __half2 nm01 = cvt_pkrtz(-mp.x, -mp.y);  // -(Mp) packed, neg in cvt
        const __half2 nm23 = cvt_pkrtz(-mp.z, -mp.w);
        #pragma unroll
        for (int p = 0; p < 4; ++p) {
            const __half2 w01 = __hfma2(A.h[p], ub2[p][0], nm01);
            const __half2 w23 = __hfma2(A.h[p], ub2[p][1], nm23);
            acc2[p][0] = __hadd2(acc2[p][0], hmax2(ze2, w01));
            acc2[p][1] = __hadd2(acc2[p][1], hmax2(ze2, w23));
        }
    }

    // ---- reductions ----
    #pragma unroll
    for (int p = 0; p < 4; ++p) {
        const float S = (__low2float(acc2[p][0]) + __high2float(acc2[p][0]))
                      + (__low2float(acc2[p][1]) + __high2float(acc2[p][1]));
        const float Sr = wred64(S);
        if (l == p) pen_sh[w][p] = Sr;
    }
    __syncthreads();

    if (t < 4) {
        float pen = 0.f;
        #pragma unroll
        for (int ww = 0; ww < 4; ++ww) pen += pen_sh[ww][t];
        out[i * NG + j0 + t] = dist0_sh[t] - 0.001f * pen;
    }
}

extern "C" void kernel_launch(void* const* d_in, const int* in_sizes, int n_in,
                              void* d_out, int out_size, void* d_ws, size_t ws_size,
                              hipStream_t stream) {
    const float* qf = (const float*)d_in[0];
    const float* x  = (const float*)d_in[1];
    const float* Mp = (const float*)d_in[2];
    const float* ze = (const float*)d_in[3];
    float* out = (float*)d_out;
    InferenceXtt_kernel<<<dim3(MQ * 64), dim3(256), 0, stream>>>(qf, x, Mp, ze, out);
}